// Round 11
// baseline (281.679 us; speedup 1.0000x reference)
//
#include <hip/hip_runtime.h>
#include <hip/hip_bf16.h>

typedef __hip_bfloat16 bf16;
typedef __attribute__((ext_vector_type(8))) short short8;   // 8 bf16 = 4 VGPRs
typedef __attribute__((ext_vector_type(4))) short short4v;  // 4 bf16 = 8 B
typedef __attribute__((ext_vector_type(4))) float float4v;

__device__ __forceinline__ float b2f(bf16 v) { return __bfloat162float(v); }
__device__ __forceinline__ bf16  f2b(float v) { return __float2bfloat16(v); }
__device__ __forceinline__ short f2s(float v) { bf16 h = f2b(v); return *reinterpret_cast<short*>(&h); }
__device__ __forceinline__ float s2f(short s) { bf16 h; *reinterpret_cast<short*>(&h) = s; return b2f(h); }
__device__ __forceinline__ short8 ld8(const bf16* p) { return *(const short8*)p; }

// Dtype-flagged input load: f32 != 0 -> buffer is fp32, else bf16.
__device__ __forceinline__ float ldin(const void* p, size_t i, int f32) {
  return f32 ? ((const float*)p)[i] : b2f(((const bf16*)p)[i]);
}

__device__ __forceinline__ float4v mfma16(short8 a, short8 b, float4v c) {
  return __builtin_amdgcn_mfma_f32_16x16x32_bf16(a, b, c, 0, 0, 0);
}

// Async 16B global -> LDS DMA. LDS dest wave-uniform; HW adds lane*16.
__device__ __forceinline__ void gload16(const void* g, void* l) {
  __builtin_amdgcn_global_load_lds((__attribute__((address_space(1))) void*)(void*)g,
                                   (__attribute__((address_space(3))) void*)l, 16, 0, 0);
}

// Constants: b=16, c=512, t=1024, 32 groups x 16ch, 8 heads, dh=64.
#define K2SCALE 0.18033688011112042f   // 0.125 * log2(e), folded into Q
#define TSTRIDE 72                     // 36 dwords == 4 mod 32: 2-way free

// ---------------------------------------------------------------------------
// Kernel 0: dtype detector (fp32-as-halfwords shows bf16 inf/NaN exponents).
// ---------------------------------------------------------------------------
__global__ __launch_bounds__(256) void detect_kernel(const unsigned short* __restrict__ x,
                                                     int* __restrict__ flag) {
  __shared__ int h;
  if (threadIdx.x == 0) h = 0;
  __syncthreads();
  int local = 0;
  for (int i = threadIdx.x; i < 8192; i += 256)
    if ((x[i] & 0x7F80u) == 0x7F80u) local = 1;
  if (local) atomicOr(&h, 1);
  __syncthreads();
  if (threadIdx.x == 0) *flag = h;
}

// ---------------------------------------------------------------------------
// Kernel 0b: convert weights + biases -> bf16 in one launch.
// ---------------------------------------------------------------------------
__global__ __launch_bounds__(256) void conv2_kernel(const void* __restrict__ s1, bf16* __restrict__ d1,
                                                    const void* __restrict__ s2, bf16* __restrict__ d2,
                                                    const void* __restrict__ s3, bf16* __restrict__ d3,
                                                    const void* __restrict__ s4, bf16* __restrict__ d4,
                                                    const int* __restrict__ flagp) {
  const int f32 = *flagp;
  const int blk = blockIdx.x;
  const void* src; bf16* dst; int base, n;
  if (blk < 768)       { src = s1; dst = d1; base = blk;        n = 786432; }
  else if (blk < 1024) { src = s2; dst = d2; base = blk - 768;  n = 262144; }
  else if (blk < 1026) { src = s3; dst = d3; base = blk - 1024; n = 1536;   }
  else                 { src = s4; dst = d4; base = 0;          n = 512;    }
  int i0 = (base * 256 + threadIdx.x) * 4;
#pragma unroll
  for (int j = 0; j < 4; j++) {
    int i = i0 + j;
    if (i < n) dst[i] = f2b(ldin(src, i, f32));
  }
}

// ---------------------------------------------------------------------------
// Kernel 1a: GroupNorm stats. One block per (b,g); writes {mean, inv}.
// ---------------------------------------------------------------------------
__global__ __launch_bounds__(256) void gn_stats_kernel(const void* __restrict__ x,
                                                       float2* __restrict__ stats,
                                                       const int* __restrict__ flagp) {
  const int f32 = *flagp;
  const int bg = blockIdx.x;
  const int GSZ = 16 * 1024;
  const size_t base = (size_t)bg * GSZ;
  const int tid = threadIdx.x;

  float s = 0.f, ss = 0.f;
  for (int i = tid; i < GSZ; i += 256) {
    float v = ldin(x, base + i, f32);
    s += v; ss += v * v;
  }
  for (int off = 32; off > 0; off >>= 1) {
    s  += __shfl_down(s, off);
    ss += __shfl_down(ss, off);
  }
  __shared__ float rs[4], rss[4];
  const int wave = tid >> 6, lane = tid & 63;
  if (lane == 0) { rs[wave] = s; rss[wave] = ss; }
  __syncthreads();
  if (tid == 0) {
    s  = rs[0] + rs[1] + rs[2] + rs[3];
    ss = rss[0] + rss[1] + rss[2] + rss[3];
    const float mean = s * (1.f / GSZ);
    const float var  = ss * (1.f / GSZ) - mean * mean;
    stats[bg] = make_float2(mean, rsqrtf(var + 1e-5f));
  }
}

// ---------------------------------------------------------------------------
// Kernel 1b: GroupNorm apply + [c][t] -> [t][c] transpose via LDS.
// ---------------------------------------------------------------------------
__global__ __launch_bounds__(256) void gn_apply_kernel(const void* __restrict__ x,
                                                       const void* __restrict__ gsc,
                                                       const void* __restrict__ gbi,
                                                       const float2* __restrict__ stats,
                                                       bf16* __restrict__ xn,
                                                       const int* __restrict__ flagp) {
  const int f32 = *flagp;
  const int b = blockIdx.y;
  const int t0 = blockIdx.x * 64;
  const int tid = threadIdx.x;

  __shared__ float Aa[512], Bb[512];
  __shared__ short T[64][130];

  for (int c = tid; c < 512; c += 256) {
    const float2 st = stats[b * 32 + (c >> 4)];
    const float s = ldin(gsc, c, f32), bi = ldin(gbi, c, f32);
    Aa[c] = st.y * s;
    Bb[c] = bi - st.x * st.y * s;
  }
  __syncthreads();

  for (int cs = 0; cs < 512; cs += 128) {
    const int t = tid & 63, c4 = tid >> 6;
#pragma unroll
    for (int i = 0; i < 32; i++) {
      const int c = cs + c4 + i * 4;
      const float v = ldin(x, ((size_t)(b * 512 + c)) * 1024 + t0 + t, f32);
      T[t][c - cs] = f2s(v * Aa[c] + Bb[c]);
    }
    __syncthreads();
    const int cc = (tid & 63) * 2, tr = tid >> 6;
#pragma unroll
    for (int i = 0; i < 16; i++) {
      const int t2 = tr + i * 4;
      const int v = *(const int*)&T[t2][cc];
      *(int*)&xn[((size_t)(b * 1024 + t0 + t2)) * 512 + cs + cc] = v;
    }
    __syncthreads();
  }
}

// ---------------------------------------------------------------------------
// Kernel 2: QKV projection. BK=32 double-buffered global_load_lds staging,
// one barrier per K-iter. 128x128 tile, 4 waves x 64x64. Q pre-scaled by
// K2SCALE. Epilogues LDS-transposed (TSTRIDE) -> full-line stores.
// ---------------------------------------------------------------------------
__global__ __launch_bounds__(256) void qkv_kernel(const bf16* __restrict__ Wb,
                                                  const bf16* __restrict__ biasb,
                                                  const bf16* __restrict__ xn,
                                                  bf16* __restrict__ Qt,
                                                  bf16* __restrict__ Kt,
                                                  bf16* __restrict__ Vb) {
  const int bat = blockIdx.z;
  const int M0 = blockIdx.y * 128;       // o
  const int N0 = blockIdx.x * 128;       // t
  __shared__ short smem[18432];          // dbuf 2x(A4096|B4096) | Tt union

  const int tid = threadIdx.x;
  const int w = tid >> 6, lane = tid & 63;
  const int col = lane & 15, g = lane >> 4;
  const int wm = (w & 1) * 64, wn = (w >> 1) * 64;

  float4v acc[4][4];
#pragma unroll
  for (int i = 0; i < 4; i++)
#pragma unroll
    for (int j = 0; j < 4; j++) acc[i][j] = (float4v)(0.f);

  int srco[2], dstb[2];
#pragma unroll
  for (int i = 0; i < 2; i++) {
    const int Gb = i * 256 + w * 64;
    dstb[i] = Gb * 8;
    const int G = Gb + lane;
    srco[i] = (G >> 2) * 512 + (G & 3) * 8;
  }
  const bf16* Ab  = Wb + (size_t)M0 * 512;
  const bf16* Bb2 = xn + ((size_t)bat * 1024 + N0) * 512;

#pragma unroll
  for (int i = 0; i < 2; i++) {
    gload16(Ab + srco[i],  &smem[dstb[i]]);
    gload16(Bb2 + srco[i], &smem[4096 + dstb[i]]);
  }
  __syncthreads();

  for (int it = 0; it < 16; ++it) {
    const int pb = it & 1;
    if (it < 15) {
      const int kn = it * 32 + 32;
      const int nb = (1 - pb) * 8192;
#pragma unroll
      for (int i = 0; i < 2; i++) {
        gload16(Ab + kn + srco[i],  &smem[nb + dstb[i]]);
        gload16(Bb2 + kn + srco[i], &smem[nb + 4096 + dstb[i]]);
      }
    }
    const short* Ap = &smem[pb * 8192];
    const short* Bp = Ap + 4096;
    short8 af[4], bf4[4];
#pragma unroll
    for (int mt = 0; mt < 4; mt++) af[mt] = *(const short8*)&Ap[(wm + mt * 16 + col) * 32 + g * 8];
#pragma unroll
    for (int nt = 0; nt < 4; nt++) bf4[nt] = *(const short8*)&Bp[(wn + nt * 16 + col) * 32 + g * 8];
#pragma unroll
    for (int mt = 0; mt < 4; mt++)
#pragma unroll
      for (int nt = 0; nt < 4; nt++) acc[mt][nt] = mfma16(af[mt], bf4[nt], acc[mt][nt]);
    __syncthreads();
  }

  // ---- epilogue ----
  const int sec = (M0 + wm) >> 6;
  const int h = sec / 3, kind = sec % 3; // 0=Q 1=K 2=V
  const size_t bh = (size_t)bat * 8 + h;
  const float qs = (kind == 0) ? K2SCALE : 1.f;
  short* Tw = smem + w * 4608;

  float bv[4][4];
#pragma unroll
  for (int mt = 0; mt < 4; mt++)
#pragma unroll
    for (int r = 0; r < 4; r++) bv[mt][r] = b2f(biasb[M0 + wm + mt * 16 + g * 4 + r]);

  if (kind == 2) {                       // V -> [c][t]
#pragma unroll
    for (int mt = 0; mt < 4; mt++)
#pragma unroll
      for (int nt = 0; nt < 4; nt++)
#pragma unroll
        for (int r = 0; r < 4; r++) {
          const int lo = mt * 16 + g * 4 + r;
          const int lt = nt * 16 + col;
          Tw[lo * TSTRIDE + lt] = f2s(acc[mt][nt][r] + bv[mt][r]);
        }
#pragma unroll
    for (int j = 0; j < 8; j++) {
      const int lo = j * 8 + (lane >> 3);
      const int gr = lane & 7;
      short8 v = *(const short8*)&Tw[lo * TSTRIDE + gr * 8];
      *(short8*)(Vb + (bh * 64 + lo) * 1024 + N0 + wn + gr * 8) = v;
    }
  } else {                               // Q/K -> [t][c]
#pragma unroll
    for (int mt = 0; mt < 4; mt++)
#pragma unroll
      for (int nt = 0; nt < 4; nt++) {
        short4v pk;
#pragma unroll
        for (int r = 0; r < 4; r++) pk[r] = f2s((acc[mt][nt][r] + bv[mt][r]) * qs);
        *(short4v*)&Tw[(nt * 16 + col) * TSTRIDE + mt * 16 + g * 4] = pk;
      }
    bf16* dst = (kind == 0) ? Qt : Kt;
#pragma unroll
    for (int j = 0; j < 8; j++) {
      const int tl = j * 8 + (lane >> 3), c8 = (lane & 7) * 8;
      short8 v = *(const short8*)&Tw[tl * TSTRIDE + c8];
      *(short8*)(dst + (bh * 1024 + N0 + wn + tl) * 64 + c8) = v;
    }
  }
}

// ---------------------------------------------------------------------------
// Kernel 3: flash attention, pipeline v2. K single-buffered, V DOUBLE-
// buffered; iter = [QK(it); barrierA; issue K(it+1)+V(it+1); softmax(it);
// PV(it); barrierB(drain)] -> DMA has softmax+PV (~600 cyc) to land.
// P staged in exact A-frag order: writer short4 scatter (4/bank optimal),
// reader ONE contiguous ds_read_b128 per frag (8/bank optimal), zero pad.
// LDS = 8(K) + 16(Vdb) + 16(PlA) = 40 KB -> 4 blocks/CU.
// Fixed-ref softmax (log2, Q pre-scaled); l via MFMA ones. Grid (bh, qtile).
// ---------------------------------------------------------------------------
__global__ __launch_bounds__(256) void attn_kernel(const bf16* __restrict__ Qt,
                                                   const bf16* __restrict__ Kt,
                                                   const bf16* __restrict__ Vb,
                                                   bf16* __restrict__ xattn) {
  const int bh = blockIdx.x;             // XCD affinity dim
  const int t0 = blockIdx.y * 128;
  const int b = bh >> 3, h = bh & 7;
  const int tid = threadIdx.x;
  const int w = tid >> 6, lane = tid & 63;
  const int col = lane & 15, g = lane >> 4;
  const int qrow0 = t0 + w * 32;

  __shared__ short S[20480];             // Ks[0,4096) | Vs2[4096,12288) | PlA[12288,20480)

  const bf16* kbase = Kt + (size_t)bh * 65536;   // [t][c]
  const bf16* vbase = Vb + (size_t)bh * 65536;   // [c][t]

  int kofs[2], vofs[2];
#pragma unroll
  for (int i = 0; i < 2; i++) {
    const int G = w * 128 + i * 64 + lane;
    const int r = G >> 3, cg = G & 7;
    const int cs = (cg ^ (r & 7)) << 3;  // granule swizzle (64-short rows)
    kofs[i] = r * 64 + cs;
    vofs[i] = r * 1024 + cs;
  }
  const int lds0 = w * 1024, lds1 = w * 1024 + 512;
  const int kswz = (col & 7);

  short8 qf[2][2];
#pragma unroll
  for (int nf = 0; nf < 2; nf++)
#pragma unroll
    for (int kf = 0; kf < 2; kf++)
      qf[nf][kf] = ld8(Qt + ((size_t)bh * 1024 + qrow0 + nf * 16 + col) * 64 + kf * 32 + g * 8);

  short8 kones;
#pragma unroll
  for (int i = 0; i < 8; i++) kones[i] = (short)0x3F80;

  float4v O[2][4], Ol[2];
#pragma unroll
  for (int mi = 0; mi < 2; mi++) {
    Ol[mi] = (float4v)(0.f);
#pragma unroll
    for (int f = 0; f < 4; f++) O[mi][f] = (float4v)(0.f);
  }

  short* Pw = S + 12288 + w * 2048;      // per-wave P, A-frag order

  // preload K(0) -> Ks, V(0) -> Vs[0]
  gload16(kbase + kofs[0], &S[lds0]);
  gload16(kbase + kofs[1], &S[lds1]);
  gload16(vbase + vofs[0], &S[4096 + lds0]);
  gload16(vbase + vofs[1], &S[4096 + lds1]);
  __syncthreads();

  for (int it = 0; it < 16; ++it) {
    const int pb = it & 1;

    // ---- QK(it): consumes Ks ----
    float4v ST[4][2];
#pragma unroll
    for (int si = 0; si < 4; si++)
#pragma unroll
      for (int nf = 0; nf < 2; nf++) ST[si][nf] = (float4v)(0.f);
#pragma unroll
    for (int kf = 0; kf < 2; kf++) {
      short8 kfr[4];
#pragma unroll
      for (int si = 0; si < 4; si++)
        kfr[si] = *(const short8*)&S[(si * 16 + col) * 64 + (((kf * 4 + g) ^ kswz) << 3)];
#pragma unroll
      for (int si = 0; si < 4; si++)
#pragma unroll
        for (int nf = 0; nf < 2; nf++)
          ST[si][nf] = mfma16(kfr[si], qf[nf][kf], ST[si][nf]);
    }

    __syncthreads();                     // A: all waves done reading Ks

    // ---- issue K(it+1) -> Ks, V(it+1) -> Vs[alt] ----
    if (it < 15) {
      gload16(kbase + (it + 1) * 4096 + kofs[0], &S[lds0]);
      gload16(kbase + (it + 1) * 4096 + kofs[1], &S[lds1]);
      const int valt = 4096 + (1 - pb) * 4096;
      gload16(vbase + (it + 1) * 64 + vofs[0], &S[valt + lds0]);
      gload16(vbase + (it + 1) * 64 + vofs[1], &S[valt + lds1]);
    }

    // ---- softmax(it): p = exp2(score), scatter to PlA in A-frag order ----
#pragma unroll
    for (int si = 0; si < 4; si++)
#pragma unroll
      for (int nf = 0; nf < 2; nf++) {
        short4v pk;
#pragma unroll
        for (int r = 0; r < 4; r++) pk[r] = f2s(exp2f(ST[si][nf][r]));
        *(short4v*)&Pw[(nf * 2 + (si >> 1)) * 512 + ((si & 1) * 2 + (g >> 1)) * 128
                       + col * 8 + (g & 1) * 4] = pk;
      }

    // ---- PV(it): consumes Vs[pb] + PlA (contiguous b128 reads) ----
    const short* Vp = &S[4096 + pb * 4096];
    short8 pa[2][2];
#pragma unroll
    for (int mi = 0; mi < 2; mi++)
#pragma unroll
      for (int kf = 0; kf < 2; kf++)
        pa[mi][kf] = *(const short8*)&Pw[(mi * 2 + kf) * 512 + lane * 8];
#pragma unroll
    for (int kf = 0; kf < 2; kf++)
#pragma unroll
      for (int mi = 0; mi < 2; mi++) {
#pragma unroll
        for (int f = 0; f < 4; f++) {
          short8 vfr = *(const short8*)&Vp[(f * 16 + col) * 64 + (((kf * 4 + g) ^ kswz) << 3)];
          O[mi][f] = mfma16(pa[mi][kf], vfr, O[mi][f]);
        }
        Ol[mi] = mfma16(pa[mi][kf], kones, Ol[mi]);
      }

    __syncthreads();                     // B: drains K(it+1), V(it+1)
  }

  // ---- O epilogue: normalize, transpose via dead K/V space (stride 72) ----
  short* Tw = S + w * 2304;              // 4 x 2304 = 9216 <= 12288 (K+V dead)
#pragma unroll
  for (int mi = 0; mi < 2; mi++) {
    float inv[4];
#pragma unroll
    for (int r = 0; r < 4; r++) inv[r] = 1.f / Ol[mi][r];
#pragma unroll
    for (int f = 0; f < 4; f++)
#pragma unroll
      for (int r = 0; r < 4; r++) {
        const int lo = mi * 16 + g * 4 + r;
        const int lc = f * 16 + col;
        Tw[lo * TSTRIDE + lc] = f2s(O[mi][f][r] * inv[r]);
      }
  }
#pragma unroll
  for (int j = 0; j < 4; j++) {
    const int lo = j * 8 + (lane >> 3);
    const int gr = lane & 7;
    short8 v = *(const short8*)&Tw[lo * TSTRIDE + gr * 8];
    *(short8*)(xattn + ((size_t)b * 1024 + qrow0 + lo) * 512 + h * 64 + gr * 8) = v;
  }
}

// ---------------------------------------------------------------------------
// Kernel 4: proj GEMM, 64x128 tile (grid 1024 = 4 blocks/CU for latency
// hiding), BK=32 dbuf one-barrier staging. out = Wp*xattn + bias + x.
// ---------------------------------------------------------------------------
__global__ __launch_bounds__(256) void proj_kernel(const bf16* __restrict__ Wp,
                                                   const bf16* __restrict__ biasb,
                                                   const bf16* __restrict__ xattn,
                                                   const void* __restrict__ res,
                                                   void* __restrict__ out,
                                                   const int* __restrict__ flagp) {
  const int f32 = *flagp;
  const int bat = blockIdx.z;
  const int M0 = blockIdx.y * 64;        // o
  const int N0 = blockIdx.x * 128;       // t
  __shared__ short smem[12288];          // dbuf 2x(A2048|B4096) | Tt union

  const int tid = threadIdx.x;
  const int w = tid >> 6, lane = tid & 63;
  const int col = lane & 15, g = lane >> 4;
  const int wm = (w & 1) * 32, wn = (w >> 1) * 64;

  float4v acc[2][4];
#pragma unroll
  for (int i = 0; i < 2; i++)
#pragma unroll
    for (int j = 0; j < 4; j++) acc[i][j] = (float4v)(0.f);

  // A: 64x32 = 256 granules (1 instr/wave); B: 128x32 = 512 (2 instr/wave)
  const int GA = w * 64 + lane;
  const int srcA = (GA >> 2) * 512 + (GA & 3) * 8;
  const int dstA = (w * 64) * 8;
  int srcB[2], dstB[2];
#pragma unroll
  for (int i = 0; i < 2; i++) {
    const int Gb = i * 256 + w * 64;
    dstB[i] = 2048 + Gb * 8;
    const int G = Gb + lane;
    srcB[i] = (G >> 2) * 512 + (G & 3) * 8;
  }
  const bf16* Ab  = Wp + (size_t)M0 * 512;
  const bf16* Bb2 = xattn + ((size_t)bat * 1024 + N0) * 512;

  gload16(Ab + srcA, &smem[dstA]);
#pragma unroll
  for (int i = 0; i < 2; i++) gload16(Bb2 + srcB[i], &smem[dstB[i]]);
  __syncthreads();

  for (int it = 0; it < 16; ++it) {
    const int pb = it & 1;
    if (it < 15) {
      const int kn = it * 32 + 32;
      const int nb = (1 - pb) * 6144;
      gload16(Ab + kn + srcA, &smem[nb + dstA]);
#pragma unroll
      for (int i = 0; i < 2; i++) gload16(Bb2 + kn + srcB[i], &smem[nb + dstB[i]]);
    }
    const short* Ap = &smem[pb * 6144];
    const short* Bp = Ap + 2048;
    short8 af[2], bf4[4];
#pragma unroll
    for (int mt = 0; mt < 2; mt++) af[mt] = *(const short8*)&Ap[(wm + mt * 16 + col) * 32 + g * 8];
#pragma unroll
    for (int nt = 0; nt < 4; nt++) bf4[nt] = *(const short8*)&Bp[(wn + nt * 16 + col) * 32 + g * 8];
#pragma unroll
    for (int mt = 0; mt < 2; mt++)
#pragma unroll
      for (int nt = 0; nt < 4; nt++) acc[mt][nt] = mfma16(af[mt], bf4[nt], acc[mt][nt]);
    __syncthreads();
  }

  // ---- epilogue: transpose to [o][t] rows via stride-TSTRIDE wave tile ----
  short* Tw = smem + w * 2304;           // 32 x 72 per wave, 9216 <= 12288
  float bv[2][4];
#pragma unroll
  for (int mt = 0; mt < 2; mt++)
#pragma unroll
    for (int r = 0; r < 4; r++) bv[mt][r] = b2f(biasb[M0 + wm + mt * 16 + g * 4 + r]);

#pragma unroll
  for (int mt = 0; mt < 2; mt++)
#pragma unroll
    for (int nt = 0; nt < 4; nt++)
#pragma unroll
      for (int r = 0; r < 4; r++) {
        const int lo = mt * 16 + g * 4 + r;           // local o 0..31
        const int lt = nt * 16 + col;                 // local t 0..63
        Tw[lo * TSTRIDE + lt] = f2s(acc[mt][nt][r] + bv[mt][r]);
      }
#pragma unroll
  for (int j = 0; j < 4; j++) {
    const int lo = j * 8 + (lane >> 3);
    const int gr = lane & 7;
    short8 v = *(const short8*)&Tw[lo * TSTRIDE + gr * 8];
    const int o = M0 + wm + lo;
    const size_t ci = ((size_t)bat * 512 + o) * 1024 + N0 + wn + gr * 8;
    if (f32) {
      float4v o0, o1;
#pragma unroll
      for (int e = 0; e < 4; e++) o0[e] = s2f(v[e]) + ((const float*)res)[ci + e];
#pragma unroll
      for (int e = 0; e < 4; e++) o1[e] = s2f(v[e + 4]) + ((const float*)res)[ci + 4 + e];
      *(float4v*)((float*)out + ci) = o0;
      *(float4v*)((float*)out + ci + 4) = o1;
    } else {
      short8 ov;
#pragma unroll
      for (int e = 0; e < 8; e++)
        ov[e] = f2s(s2f(v[e]) + b2f(((const bf16*)res)[ci + e]));
      *(short8*)((bf16*)out + ci) = ov;
    }
  }
}

// ---------------------------------------------------------------------------
extern "C" void kernel_launch(void* const* d_in, const int* in_sizes, int n_in,
                              void* d_out, int out_size, void* d_ws, size_t ws_size,
                              hipStream_t stream) {
  const void* x      = d_in[0];
  const void* gsc    = d_in[1];
  const void* gbi    = d_in[2];
  const void* w_qkv  = d_in[3];
  const void* b_qkv  = d_in[4];
  const void* w_proj = d_in[5];
  const void* b_proj = d_in[6];

  char* p = (char*)d_ws;
  int*    flag  = (int*)p;                 p += 256;
  float2* stats = (float2*)p;              p += 512 * sizeof(float2);
  bf16*   xn    = (bf16*)p;                p += (size_t)16 * 1024 * 512 * 2;
  bf16*   Qt    = (bf16*)p;                p += (size_t)128 * 1024 * 64 * 2;
  bf16*   Kt    = (bf16*)p;                p += (size_t)128 * 1024 * 64 * 2;
  bf16*   Vb    = (bf16*)p;                p += (size_t)128 * 64 * 1024 * 2;
  bf16*   Wqb   = (bf16*)p;                p += (size_t)1536 * 512 * 2;
  bf16*   Wpb   = (bf16*)p;                p += (size_t)512 * 512 * 2;
  bf16*   Bqb   = (bf16*)p;                p += (size_t)1536 * 2;
  bf16*   Bpb   = (bf16*)p;                p += (size_t)512 * 2;
  bf16*   xattn = (bf16*)p;

  detect_kernel<<<1, 256, 0, stream>>>((const unsigned short*)x, flag);
  conv2_kernel<<<1027, 256, 0, stream>>>(w_qkv, Wqb, w_proj, Wpb,
                                         b_qkv, Bqb, b_proj, Bpb, flag);
  gn_stats_kernel<<<512, 256, 0, stream>>>(x, stats, flag);
  gn_apply_kernel<<<dim3(16, 16), 256, 0, stream>>>(x, gsc, gbi, stats, xn, flag);
  qkv_kernel<<<dim3(8, 12, 16), 256, 0, stream>>>(Wqb, Bqb, xn, Qt, Kt, Vb);
  attn_kernel<<<dim3(128, 8), 256, 0, stream>>>(Qt, Kt, Vb, xattn);
  proj_kernel<<<dim3(8, 8, 16), 256, 0, stream>>>(Wpb, Bpb, xattn, x, d_out, flag);
}